// Round 3
// baseline (5226.988 us; speedup 1.0000x reference)
//
#include <hip/hip_runtime.h>
#include <stdint.h>

// ---------------------------------------------------------------------------
// ODE-RNN encoder, f32 I/O, bf16 MFMA internals.
// R20: M=16 restructure for NATURAL 2-blocks/CU residency.
// History: R17 (M=32) = 108V+32A = 140 total -> 1 block/CU (24% occ).
// R18 forced 128 via launch_bounds(512,4) -> compiler spilled ~GBs to scratch
// (FETCH 39MB->1.8GB), flat. R19 (Ks->LDS, DPP reduce, natural alloc) = 100V
// +32A = 132 -> STILL 1 block/CU, but epilogue savings gave 3059->2873us.
// Occupancy law: waves/SIMD = floor(512 / total(V+A)); 8-wave blocks quantize
// residency to blocks of 8 waves -> 2 blocks/CU needs total <= 128.
// R20 change: halve block tile to M=16 (8 waves x N=64 each, j=0..3; mi loop
// gone). Per-thread: acc 16A (was 32), h 16V (was 32), ksum 8V back in regs
// (Ks LDS deleted). Est total ~100-106 <= 128 with slack -> 2 blocks/CU
// without forcing. LDS ~25KB/block. Per-CU work unchanged (2x16 rows).
// Mechanism: two INDEPENDENT barrier groups per CU -> one block's GEMM
// (MFMA) overlaps the other's epilogue (VALU/LDS latency chains), and
// 4 waves/SIMD cover the K-loop's ~200cyc L2 prefetch gap (dbuf distance
// is only ~2 kk). Also: ln_epi final loop j-outer + stat preload -> Ps
// re-reads per thread 64 -> 8.
// Carried: compiler sinks plain-load prefetches (R11); global_load_lds DMA
// round-trip unhidden (R12/R13) -> keep 2-slab global->VGPR dbuf; no
// materialized global RK4 state (R15); GRU kept simple (R15/R16).
// ---------------------------------------------------------------------------

typedef __bf16 bf16x8 __attribute__((ext_vector_type(8)));
typedef float floatx4 __attribute__((ext_vector_type(4)));

#define BP 40  // gru padded B row (ushorts)

static __device__ __forceinline__ float bf2f(unsigned short u) {
  union { unsigned int u32; float f; } c;
  c.u32 = ((unsigned int)u) << 16;
  return c.f;
}
static __device__ __forceinline__ unsigned short f2bf(float f) {
  union { __bf16 h; unsigned short u; } c;
  c.h = (__bf16)f;  // RNE
  return c.u;
}

// LDS-only barrier: does NOT drain vmcnt, so global prefetches stay in flight.
static __device__ __forceinline__ void barrier_lds() {
  __asm__ volatile("s_waitcnt lgkmcnt(0)\n\ts_barrier" ::: "memory");
}

// VALU-only 16-lane row sum via DPP row_shr chain; full sum lands in the top
// lane (ml==15) of each 16-lane row.
static __device__ __forceinline__ float row16_sum(float v) {
  union { float f; int i; } c, d;
  c.f = v;
  d.i = __builtin_amdgcn_update_dpp(0, c.i, 0x111, 0xf, 0xf, true); c.f += d.f;
  d.i = __builtin_amdgcn_update_dpp(0, c.i, 0x112, 0xf, 0xf, true); c.f += d.f;
  d.i = __builtin_amdgcn_update_dpp(0, c.i, 0x114, 0xf, 0xf, true); c.f += d.f;
  d.i = __builtin_amdgcn_update_dpp(0, c.i, 0x118, 0xf, 0xf, true); c.f += d.f;
  return c.f;
}

// ---------------------------------------------------------------------------
// tile_weight: W (K=512 x N=512, f32 row-major) -> bf16 tiled
// [kk(16)][nt(32)][qd(4)][ml(16)][8]; element (kk,nt,qd,ml,j) = W[kk*32+qd*8+j][nt*16+ml]
// ---------------------------------------------------------------------------
__global__ void tile_weight(const float* __restrict__ src, unsigned short* __restrict__ dst) {
  int t = blockIdx.x * 256 + threadIdx.x;  // 0..32767
  int ml = t & 15, qd = (t >> 4) & 3;
  int nt = (t >> 6) & 31, kk = t >> 11;
  int n = nt * 16 + ml;
  int k0 = kk * 32 + qd * 8;
  unsigned short o[8] __attribute__((aligned(16)));
#pragma unroll
  for (int j = 0; j < 8; ++j) o[j] = f2bf(src[(size_t)(k0 + j) * 512 + n]);
  *(uint4*)(dst + (size_t)t * 8) = *(const uint4*)o;
}

// ---------------------------------------------------------------------------
// transpose + f32->bf16 (GRU weights, [n][k] flat layout)
// ---------------------------------------------------------------------------
__global__ void transpose_f2b(const float* __restrict__ src, unsigned short* __restrict__ dst,
                              int R, int C) {
  __shared__ float t[32][33];
  int c0 = blockIdx.x * 32, r0 = blockIdx.y * 32;
  int tx = threadIdx.x, ty = threadIdx.y;  // 32 x 8
#pragma unroll
  for (int i = 0; i < 32; i += 8) t[ty + i][tx] = src[(size_t)(r0 + ty + i) * C + c0 + tx];
  __syncthreads();
#pragma unroll
  for (int i = 0; i < 32; i += 8) dst[(size_t)(c0 + ty + i) * R + r0 + tx] = f2bf(t[tx][ty + i]);
}

// ---------------------------------------------------------------------------
// obs embed: y = leaky(LN(xs @ W + b)) (f32 in, bf16 out), one wave per row
// ---------------------------------------------------------------------------
__global__ __launch_bounds__(256) void obs_embed(
    const float* __restrict__ xs, const float* __restrict__ W,
    const float* __restrict__ bias, const float* __restrict__ gam,
    const float* __restrict__ bet, unsigned short* __restrict__ Y) {
  __shared__ float Wl[4096];
  const int tid = threadIdx.x, lane = tid & 63, wv = tid >> 6;
#pragma unroll
  for (int i = 0; i < 16; ++i) Wl[i * 256 + tid] = W[i * 256 + tid];
  __syncthreads();
  size_t row = (size_t)blockIdx.x * 4 + wv;
  float xf[8];
  {
    const float* xp = xs + row * 8;
#pragma unroll
    for (int k = 0; k < 8; ++k) xf[k] = xp[k];
  }
  int n0 = lane * 8;
  float a[8];
#pragma unroll
  for (int j = 0; j < 8; ++j) a[j] = bias[n0 + j];
#pragma unroll
  for (int k = 0; k < 8; ++k)
#pragma unroll
    for (int j = 0; j < 8; ++j) a[j] += xf[k] * Wl[k * 512 + n0 + j];
  float s1 = 0.f, s2 = 0.f;
#pragma unroll
  for (int j = 0; j < 8; ++j) { s1 += a[j]; s2 += a[j] * a[j]; }
#pragma unroll
  for (int off = 1; off < 64; off <<= 1) { s1 += __shfl_xor(s1, off); s2 += __shfl_xor(s2, off); }
  float mean = s1 * (1.f / 512.f);
  float rstd = rsqrtf(s2 * (1.f / 512.f) - mean * mean + 1e-5f);
  unsigned short o[8] __attribute__((aligned(16)));
#pragma unroll
  for (int j = 0; j < 8; ++j) {
    float v = (a[j] - mean) * rstd * gam[n0 + j] + bet[n0 + j];
    v = v > 0.f ? v : 0.01f * v;
    o[j] = f2bf(v);
  }
  *(uint4*)(Y + row * 512 + n0) = *(const uint4*)o;
}

// ---------------------------------------------------------------------------
// ODE megakernel, M=16 per block. A (16x512) resident in tiled LDS
// [nt(16)][sub(4)][ml(16)][8]; 8 waves, each owning all 16 rows x N=64
// (nt = 4*wv .. 4*wv+3). B fragments stream global->VGPR dbuf; K-loop
// barrier-free.
// ---------------------------------------------------------------------------

// element (row, n) address in tiled A (ushort index), row < 16
static __device__ __forceinline__ int a16(int row, int n) {
  return (((n >> 5) * 4 + ((n >> 3) & 3)) * 128) + row * 8 + (n & 7);
}

static __device__ __forceinline__ void bload(const unsigned short* __restrict__ Wt, int kk,
                                             int wv, int lane, bf16x8 (&b)[4]) {
#pragma unroll
  for (int j = 0; j < 4; ++j)
    b[j] = *(const bf16x8*)(Wt + ((size_t)kk * 32 + 4 * wv + j) * 512 + (size_t)lane * 8);
}

// bb must hold Wt slabs {0,1} on entry; holds Wnext slabs {0,1} on exit.
static __device__ __forceinline__ void gemmS(const unsigned short* __restrict__ Wt,
                                             const unsigned short* __restrict__ Wnext,
                                             const unsigned short* As, int wv, int lane,
                                             bf16x8 (&bb)[2][4], floatx4 (&acc)[4]) {
#pragma unroll
  for (int j = 0; j < 4; ++j) acc[j] = 0.f;
#pragma unroll 2
  for (int kk = 0; kk < 16; ++kk) {  // unroll 2 (dbuf parity), NOT full (R5-R8 lesson)
    bf16x8 a = *(const bf16x8*)&As[kk * 512 + lane * 8];
#pragma unroll
    for (int j = 0; j < 4; ++j)
      acc[j] = __builtin_amdgcn_mfma_f32_16x16x32_bf16(a, bb[kk & 1][j], acc[j], 0, 0, 0);
    // refill the just-consumed slot: kk+2 of this weight, or next weight's 0/1
    if (kk < 14) bload(Wt, kk + 2, wv, lane, bb[kk & 1]);
    else bload(Wnext, kk - 14, wv, lane, bb[kk & 1]);
  }
}

// LN + leaky epilogue; 8-wave reduction; writes bf16 result into tiled As.
static __device__ __forceinline__ void ln_epi(floatx4 (&acc)[4], unsigned short* As,
                                              const unsigned short* Ps, int pb, int pg, int pbe,
                                              bool addt, float tval, int wv, int lane, int tid,
                                              float2* red, float* stat) {
  const int ml = lane & 15, qd = lane >> 4;
#pragma unroll
  for (int j = 0; j < 4; ++j) {
    int n = (4 * wv + j) * 16 + ml;
    float bias = bf2f(Ps[pb * 512 + n]);
    if (addt) bias += tval * bf2f(Ps[512 + n]);
#pragma unroll
    for (int r = 0; r < 4; ++r) acc[j][r] += bias;
  }
#pragma unroll
  for (int r = 0; r < 4; ++r) {
    float s1 = 0.f, s2 = 0.f;
#pragma unroll
    for (int j = 0; j < 4; ++j) { float x = acc[j][r]; s1 += x; s2 += x * x; }
    s1 = row16_sum(s1);
    s2 = row16_sum(s2);
    if (ml == 15) red[(4 * qd + r) * 8 + wv] = make_float2(s1, s2);
  }
  barrier_lds();  // red visible; all waves past their As a-frag reads
  if (tid < 16) {
    float S1 = 0.f, S2 = 0.f;
#pragma unroll
    for (int w = 0; w < 8; ++w) { float2 v = red[tid * 8 + w]; S1 += v.x; S2 += v.y; }
    float mean = S1 * (1.f / 512.f);
    float var = S2 * (1.f / 512.f) - mean * mean;
    stat[tid * 2] = mean;
    stat[tid * 2 + 1] = rsqrtf(var + 1e-5f);
  }
  barrier_lds();
  // preload per-row stats (4 rows/thread), then j-outer so gamma/beta are
  // read ONCE per n (8 Ps reads/thread total, was 64 at M=32 ordering)
  float mr[4][2];
#pragma unroll
  for (int r = 0; r < 4; ++r) {
    int row = 4 * qd + r;
    mr[r][0] = stat[row * 2];
    mr[r][1] = stat[row * 2 + 1];
  }
#pragma unroll
  for (int j = 0; j < 4; ++j) {
    int n = (4 * wv + j) * 16 + ml;
    float gm = bf2f(Ps[pg * 512 + n]);
    float bt = bf2f(Ps[pbe * 512 + n]);
#pragma unroll
    for (int r = 0; r < 4; ++r) {
      float x = (acc[j][r] - mr[r][0]) * mr[r][1] * gm + bt;
      x = x > 0.f ? x : 0.01f * x;
      As[a16(4 * qd + r, n)] = f2bf(x);
    }
  }
  barrier_lds();  // As writes visible
}

// RK4 stage: k = acc + bout; h fp32 regs, ksum packed bf16 pairs in regs;
// writes y into As; on the final stage also writes h_ode to Yb.
static __device__ __forceinline__ void stage_epi(floatx4 (&acc)[4], float (&h)[4][4],
                                                 unsigned int (&ks)[4][2], unsigned short* As,
                                                 unsigned short* Yb, size_t m0,
                                                 const unsigned short* Ps, int stg, bool last,
                                                 int wv, int lane) {
  const int ml = lane & 15, qd = lane >> 4;
  barrier_lds();  // K-loop has no barriers: ensure all waves done reading As
#pragma unroll
  for (int j = 0; j < 4; ++j) {
    int n = (4 * wv + j) * 16 + ml;
    float bias = bf2f(Ps[7 * 512 + n]);
#pragma unroll
    for (int rp = 0; rp < 2; ++rp) {
      float kv0 = acc[j][2 * rp] + bias;
      float kv1 = acc[j][2 * rp + 1] + bias;
      unsigned int pk = ks[j][rp];
      float s0 = bf2f((unsigned short)(pk & 0xffffu));
      float s1 = bf2f((unsigned short)(pk >> 16));
      float h0 = h[j][2 * rp], h1 = h[j][2 * rp + 1];
      float y0, y1;
      if (stg == 0)      { s0 = kv0;        s1 = kv1;        y0 = h0 + 0.125f * kv0; y1 = h1 + 0.125f * kv1; }
      else if (stg == 1) { s0 += 2.f * kv0; s1 += 2.f * kv1; y0 = h0 + 0.125f * kv0; y1 = h1 + 0.125f * kv1; }
      else if (stg == 2) { s0 += 2.f * kv0; s1 += 2.f * kv1; y0 = h0 + 0.25f * kv0;  y1 = h1 + 0.25f * kv1; }
      else {
        h0 += (1.f / 24.f) * (s0 + kv0);  // dt/6, dt=0.25
        h1 += (1.f / 24.f) * (s1 + kv1);
        h[j][2 * rp] = h0; h[j][2 * rp + 1] = h1;
        y0 = h0; y1 = h1;
      }
      ks[j][rp] = (unsigned int)f2bf(s0) | ((unsigned int)f2bf(s1) << 16);
      int row = 4 * qd + 2 * rp;
      As[a16(row, n)] = f2bf(y0);
      As[a16(row + 1, n)] = f2bf(y1);
      if (last && stg == 3) {
        Yb[(m0 + row) * 512 + n] = f2bf(y0);
        Yb[(m0 + row + 1) * 512 + n] = f2bf(y1);
      }
    }
  }
  barrier_lds();  // As writes visible
}

__global__ __launch_bounds__(512) void ode_mega(
    unsigned short* Yb, const unsigned short* __restrict__ W1t,
    const unsigned short* __restrict__ W2t, const unsigned short* __restrict__ Wot,
    const float* __restrict__ b1, const float* __restrict__ tr, const float* __restrict__ g1,
    const float* __restrict__ be1, const float* __restrict__ b2, const float* __restrict__ g2,
    const float* __restrict__ be2, const float* __restrict__ bo) {
  __shared__ __align__(16) unsigned short As[8192];   // 16KB tiled A (16 rows)
  __shared__ __align__(16) unsigned short Ps[4096];   // 8KB params
  __shared__ float2 red[128];                         // 1KB: 16 rows x 8 waves
  __shared__ float stat[32];                          // 128B -> ~25.1KB/block

  const int tid = threadIdx.x;
  const int lane = tid & 63;
  const int wv = tid >> 6;  // 0..7
  const int ml = lane & 15;
  const int qd = lane >> 4;
  const size_t m0 = (size_t)blockIdx.x * 16;

  // start weight prefetch immediately
  bf16x8 bb[2][4];
  bload(W1t, 0, wv, lane, bb[0]);
  bload(W1t, 1, wv, lane, bb[1]);

  {
    const float* srcs[8] = {b1, tr, g1, be1, b2, g2, be2, bo};
#pragma unroll
    for (int v = 0; v < 8; ++v) Ps[v * 512 + tid] = f2bf(srcs[v][tid]);
  }
  // stage As: thread owns row r = tid>>5, chunks c = (tid&31) and (tid&31)+32
  {
    int r = tid >> 5;        // 0..15
    int c2 = tid & 31;
#pragma unroll
    for (int i = 0; i < 2; ++i) {
      int c = c2 + i * 32;   // 0..63 (8-ushort chunks per row)
      uint4 v = *(const uint4*)(Yb + (m0 + r) * 512 + c * 8);
      int dst = ((c >> 2) * 4 + (c & 3)) * 128 + r * 8;
      *(uint4*)(As + dst) = v;
    }
  }
  barrier_lds();

  float h[4][4];          // fp32 ODE state, MFMA C-layout (16 elems/thread)
  unsigned int ks[4][2];  // RK4 ksum, packed bf16 pairs
#pragma unroll
  for (int j = 0; j < 4; ++j) {
    ks[j][0] = 0u; ks[j][1] = 0u;
    int n = (4 * wv + j) * 16 + ml;
#pragma unroll
    for (int r = 0; r < 4; ++r) h[j][r] = bf2f(As[a16(4 * qd + r, n)]);
  }

  for (int e = 0; e < 16; ++e) {  // 4 RK4 steps x 4 stages
    int stg = e & 3;
    float tval = 0.25f * (float)(e >> 2) + ((stg == 3) ? 0.25f : (stg ? 0.125f : 0.f));
    floatx4 acc[4];
    gemmS(W1t, W2t, As, wv, lane, bb, acc);
    ln_epi(acc, As, Ps, 0, 2, 3, true, tval, wv, lane, tid, red, stat);
    gemmS(W2t, Wot, As, wv, lane, bb, acc);
    ln_epi(acc, As, Ps, 4, 5, 6, false, 0.f, wv, lane, tid, red, stat);
    gemmS(Wot, W1t, As, wv, lane, bb, acc);  // preloads next eval's W1
    stage_epi(acc, h, ks, As, Yb, m0, Ps, stg, e == 15, wv, lane);
  }
}

// ---------------------------------------------------------------------------
// GRU step: gi = y_t @ W_ih, gh = h_prev @ W_hh, gates.
// grid (32, 8): 32 rows x 64 gate-cols per block, 4 waves.
// ---------------------------------------------------------------------------
__global__ __launch_bounds__(256) void gru_step(
    const unsigned short* __restrict__ Yt, const float* __restrict__ hprev,
    float* __restrict__ hnew, const unsigned short* __restrict__ Wiht,
    const unsigned short* __restrict__ Whht, const float* __restrict__ bih,
    const float* __restrict__ bhh) {
  __shared__ __align__(16) unsigned short Ay[32 * BP];
  __shared__ __align__(16) unsigned short Ah[32 * BP];
  __shared__ __align__(16) unsigned short Bg[6 * 64 * BP];
  const int tid = threadIdx.x, lane = tid & 63, wv = tid >> 6;
  const int ml = lane & 15, qd = lane >> 4;
  const int m0 = blockIdx.x * 32;
  const int j0 = blockIdx.y * 64;

  floatx4 acc[2][6];
#pragma unroll
  for (int mi = 0; mi < 2; ++mi)
#pragma unroll
    for (int g = 0; g < 6; ++g) acc[mi][g] = 0.f;

  for (int kk = 0; kk < 16; ++kk) {
    __syncthreads();
#pragma unroll
    for (int c = 0; c < 7; ++c) {
      int id = c * 256 + tid;
      if (id < 128) {
        int r = id >> 2, kc = id & 3;
        *(uint4*)(Ay + r * BP + kc * 8) =
            *(const uint4*)(Yt + (size_t)(m0 + r) * 512 + kk * 32 + kc * 8);
      } else if (id < 256) {
        int id2 = id - 128;
        int r = id2 >> 2, kc = id2 & 3;
        const float* s = hprev + (size_t)(m0 + r) * 512 + kk * 32 + kc * 8;
        unsigned short o[8] __attribute__((aligned(16)));
#pragma unroll
        for (int j = 0; j < 8; ++j) o[j] = f2bf(s[j]);
        *(uint4*)(Ah + r * BP + kc * 8) = *(const uint4*)o;
      } else {
        int id2 = id - 256;
        int g = id2 >> 8;
        int rem = id2 & 255;
        int r = rem >> 2, kc = rem & 3;
        const unsigned short* mat = (g < 3) ? Wiht : Whht;
        int gate = (g < 3) ? g : (g - 3);
        *(uint4*)(Bg + g * (64 * BP) + r * BP + kc * 8) =
            *(const uint4*)(mat + (size_t)(gate * 512 + j0 + r) * 512 + kk * 32 + kc * 8);
      }
    }
    __syncthreads();
    bf16x8 ay[2], ah[2];
#pragma unroll
    for (int mi = 0; mi < 2; ++mi) {
      ay[mi] = *(const bf16x8*)&Ay[(16 * mi + ml) * BP + qd * 8];
      ah[mi] = *(const bf16x8*)&Ah[(16 * mi + ml) * BP + qd * 8];
    }
#pragma unroll
    for (int g = 0; g < 6; ++g) {
      bf16x8 b = *(const bf16x8*)&Bg[g * (64 * BP) + (16 * wv + ml) * BP + qd * 8];
#pragma unroll
      for (int mi = 0; mi < 2; ++mi)
        acc[mi][g] = __builtin_amdgcn_mfma_f32_16x16x32_bf16((g < 3) ? ay[mi] : ah[mi], b,
                                                             acc[mi][g], 0, 0, 0);
    }
  }
  int j = j0 + 16 * wv + ml;
  float bi_r = bih[j], bi_z = bih[512 + j], bi_n = bih[1024 + j];
  float bh_r = bhh[j], bh_z = bhh[512 + j], bh_n = bhh[1024 + j];
#pragma unroll
  for (int mi = 0; mi < 2; ++mi)
#pragma unroll
    for (int r = 0; r < 4; ++r) {
      size_t row = (size_t)(m0 + 16 * mi + 4 * qd + r);
      float rg = acc[mi][0][r] + bi_r + acc[mi][3][r] + bh_r;
      rg = 1.f / (1.f + __expf(-rg));
      float zg = acc[mi][1][r] + bi_z + acc[mi][4][r] + bh_z;
      zg = 1.f / (1.f + __expf(-zg));
      float ng = tanhf(acc[mi][2][r] + bi_n + rg * (acc[mi][5][r] + bh_n));
      float hp = hprev[row * 512 + j];
      hnew[row * 512 + j] = (1.f - zg) * ng + zg * hp;
    }
}

__global__ void zero_h(float* hf) {
  int i = blockIdx.x * 256 + threadIdx.x;
  hf[i] = 0.f;
}

// ---------------------------------------------------------------------------
extern "C" void kernel_launch(void* const* d_in, const int* in_sizes, int n_in,
                              void* d_out, int out_size, void* d_ws, size_t ws_size,
                              hipStream_t stream) {
  (void)in_sizes; (void)n_in; (void)out_size; (void)ws_size;
  const float* xs    = (const float*)d_in[0];
  const float* obsW  = (const float*)d_in[1];
  const float* obsb  = (const float*)d_in[2];
  const float* obsg  = (const float*)d_in[3];
  const float* obsbe = (const float*)d_in[4];
  const float* W1    = (const float*)d_in[5];
  const float* b1    = (const float*)d_in[6];
  const float* g1    = (const float*)d_in[7];
  const float* be1   = (const float*)d_in[8];
  const float* W2    = (const float*)d_in[9];
  const float* b2    = (const float*)d_in[10];
  const float* g2    = (const float*)d_in[11];
  const float* be2   = (const float*)d_in[12];
  const float* Wo    = (const float*)d_in[13];
  const float* bo    = (const float*)d_in[14];
  const float* Wih   = (const float*)d_in[15];
  const float* bih   = (const float*)d_in[16];
  const float* Whh   = (const float*)d_in[17];
  const float* bhh   = (const float*)d_in[18];

  char* p = (char*)d_ws;
  auto take = [&](size_t bytes) { char* q = p; p += (bytes + 255) & ~(size_t)255; return q; };
  unsigned short* W1t  = (unsigned short*)take((size_t)512 * 512 * 2);
  unsigned short* W2t  = (unsigned short*)take((size_t)512 * 512 * 2);
  unsigned short* Wot  = (unsigned short*)take((size_t)512 * 512 * 2);
  unsigned short* Wiht = (unsigned short*)take((size_t)1536 * 512 * 2);
  unsigned short* Whht = (unsigned short*)take((size_t)1536 * 512 * 2);
  float* hf0 = (float*)take((size_t)1024 * 512 * 4);
  float* hf1 = (float*)take((size_t)1024 * 512 * 4);
  unsigned short* Yb = (unsigned short*)take((size_t)65536 * 512 * 2);

  dim3 tb(32, 8);
  tile_weight<<<128, 256, 0, stream>>>(W1, W1t);  // first 512 of 513 rows
  tile_weight<<<128, 256, 0, stream>>>(W2, W2t);
  tile_weight<<<128, 256, 0, stream>>>(Wo, Wot);
  transpose_f2b<<<dim3(48, 16), tb, 0, stream>>>(Wih, Wiht, 512, 1536);
  transpose_f2b<<<dim3(48, 16), tb, 0, stream>>>(Whh, Whht, 512, 1536);

  obs_embed<<<16384, 256, 0, stream>>>(xs, obsW, obsb, obsg, obsbe, Yb);

  // tr = W1 row 512 (time row), folded into layer-1 bias per eval.
  ode_mega<<<4096, 512, 0, stream>>>(Yb, W1t, W2t, Wot, b1, W1 + 512 * 512, g1, be1, b2, g2,
                                     be2, bo);

  zero_h<<<2048, 256, 0, stream>>>(hf0);
  float* hf[2] = {hf0, hf1};
  for (int t = 0; t < 64; ++t) {
    int s = t & 1, d = s ^ 1;
    float* hn = (t == 63) ? (float*)d_out : hf[d];
    gru_step<<<dim3(32, 8), 256, 0, stream>>>(Yb + (size_t)t * 1024 * 512, hf[s], hn, Wiht, Whht,
                                              bih, bhh);
  }
}

// Round 4
// 3872.997 us; speedup vs baseline: 1.3496x; 1.3496x over previous
//
#include <hip/hip_runtime.h>
#include <stdint.h>

// ---------------------------------------------------------------------------
// ODE-RNN encoder, f32 I/O, bf16 MFMA internals.
// R21 = R19 structure (verified 2873us) + params-in-registers epilogues.
// Session laws (measured):
//  * Occupancy is PINNED at 1 block/CU for this kernel family: R17(108V/32A),
//    R19(100V/32A), R20(84V/16A) all 24%; only forced 64V/64A (R18) reached
//    2 blocks and it spilled GBs. The HW/compiler grant is not arch+acc
//    (even-split/2xmax-like). STOP chasing residency; arch regs 100->~125
//    are FREE (no cliff crossed).
//  * M=16 tile (R20) halves B-load amortization: MfmaUtil 27.8->17.2,
//    4480us. M=32 is right.
//  * Cycle model (validated): MFMA 28% (= measured MfmaUtil), VALU 32%,
//    ~40% stall. Epilogue Ps ds_read_u16 chains (~20/thread/eval) are a
//    prime stall+VALU component -> moved to 16 packed u32 regs (this round).
// Carried: compiler sinks plain-load prefetches (R11); global_load_lds DMA
// round-trip unhidden (R12/R13) -> 2-slab global->VGPR dbuf; no global RK4
// state (R15); GRU kept simple (R15/R16); Ks in LDS, DPP row16 reduce (R19).
// ---------------------------------------------------------------------------

typedef __bf16 bf16x8 __attribute__((ext_vector_type(8)));
typedef float floatx4 __attribute__((ext_vector_type(4)));

#define BP 40   // gru padded B row (ushorts)
#define KSP 516 // Ks row stride (uints): qd*2*516 mod 32 = 8qd -> 2-way max

static __device__ __forceinline__ float bf2f(unsigned short u) {
  union { unsigned int u32; float f; } c;
  c.u32 = ((unsigned int)u) << 16;
  return c.f;
}
static __device__ __forceinline__ unsigned short f2bf(float f) {
  union { __bf16 h; unsigned short u; } c;
  c.h = (__bf16)f;  // RNE
  return c.u;
}
// packed-bf16-pair helpers (params live as u32 = lo|hi<<16)
static __device__ __forceinline__ float lo_bf(unsigned int u) {
  union { unsigned int i; float f; } c; c.i = u << 16; return c.f;
}
static __device__ __forceinline__ float hi_bf(unsigned int u) {
  union { unsigned int i; float f; } c; c.i = u & 0xffff0000u; return c.f;
}
static __device__ __forceinline__ unsigned int pk2(float a, float b) {
  return (unsigned int)f2bf(a) | ((unsigned int)f2bf(b) << 16);
}

// LDS-only barrier: does NOT drain vmcnt, so global prefetches stay in flight.
static __device__ __forceinline__ void barrier_lds() {
  __asm__ volatile("s_waitcnt lgkmcnt(0)\n\ts_barrier" ::: "memory");
}

// VALU-only 16-lane row sum via DPP row_shr chain; full sum lands in the top
// lane (ml==15) of each 16-lane row.
static __device__ __forceinline__ float row16_sum(float v) {
  union { float f; int i; } c, d;
  c.f = v;
  d.i = __builtin_amdgcn_update_dpp(0, c.i, 0x111, 0xf, 0xf, true); c.f += d.f;
  d.i = __builtin_amdgcn_update_dpp(0, c.i, 0x112, 0xf, 0xf, true); c.f += d.f;
  d.i = __builtin_amdgcn_update_dpp(0, c.i, 0x114, 0xf, 0xf, true); c.f += d.f;
  d.i = __builtin_amdgcn_update_dpp(0, c.i, 0x118, 0xf, 0xf, true); c.f += d.f;
  return c.f;
}

// ---------------------------------------------------------------------------
// tile_weight: W (K=512 x N=512, f32 row-major) -> bf16 tiled
// [kk(16)][nt(32)][qd(4)][ml(16)][8]; element (kk,nt,qd,ml,j) = W[kk*32+qd*8+j][nt*16+ml]
// ---------------------------------------------------------------------------
__global__ void tile_weight(const float* __restrict__ src, unsigned short* __restrict__ dst) {
  int t = blockIdx.x * 256 + threadIdx.x;  // 0..32767
  int ml = t & 15, qd = (t >> 4) & 3;
  int nt = (t >> 6) & 31, kk = t >> 11;
  int n = nt * 16 + ml;
  int k0 = kk * 32 + qd * 8;
  unsigned short o[8] __attribute__((aligned(16)));
#pragma unroll
  for (int j = 0; j < 8; ++j) o[j] = f2bf(src[(size_t)(k0 + j) * 512 + n]);
  *(uint4*)(dst + (size_t)t * 8) = *(const uint4*)o;
}

// ---------------------------------------------------------------------------
// transpose + f32->bf16 (GRU weights, [n][k] flat layout)
// ---------------------------------------------------------------------------
__global__ void transpose_f2b(const float* __restrict__ src, unsigned short* __restrict__ dst,
                              int R, int C) {
  __shared__ float t[32][33];
  int c0 = blockIdx.x * 32, r0 = blockIdx.y * 32;
  int tx = threadIdx.x, ty = threadIdx.y;  // 32 x 8
#pragma unroll
  for (int i = 0; i < 32; i += 8) t[ty + i][tx] = src[(size_t)(r0 + ty + i) * C + c0 + tx];
  __syncthreads();
#pragma unroll
  for (int i = 0; i < 32; i += 8) dst[(size_t)(c0 + ty + i) * R + r0 + tx] = f2bf(t[tx][ty + i]);
}

// ---------------------------------------------------------------------------
// obs embed: y = leaky(LN(xs @ W + b)) (f32 in, bf16 out), one wave per row
// ---------------------------------------------------------------------------
__global__ __launch_bounds__(256) void obs_embed(
    const float* __restrict__ xs, const float* __restrict__ W,
    const float* __restrict__ bias, const float* __restrict__ gam,
    const float* __restrict__ bet, unsigned short* __restrict__ Y) {
  __shared__ float Wl[4096];
  const int tid = threadIdx.x, lane = tid & 63, wv = tid >> 6;
#pragma unroll
  for (int i = 0; i < 16; ++i) Wl[i * 256 + tid] = W[i * 256 + tid];
  __syncthreads();
  size_t row = (size_t)blockIdx.x * 4 + wv;
  float xf[8];
  {
    const float* xp = xs + row * 8;
#pragma unroll
    for (int k = 0; k < 8; ++k) xf[k] = xp[k];
  }
  int n0 = lane * 8;
  float a[8];
#pragma unroll
  for (int j = 0; j < 8; ++j) a[j] = bias[n0 + j];
#pragma unroll
  for (int k = 0; k < 8; ++k)
#pragma unroll
    for (int j = 0; j < 8; ++j) a[j] += xf[k] * Wl[k * 512 + n0 + j];
  float s1 = 0.f, s2 = 0.f;
#pragma unroll
  for (int j = 0; j < 8; ++j) { s1 += a[j]; s2 += a[j] * a[j]; }
#pragma unroll
  for (int off = 1; off < 64; off <<= 1) { s1 += __shfl_xor(s1, off); s2 += __shfl_xor(s2, off); }
  float mean = s1 * (1.f / 512.f);
  float rstd = rsqrtf(s2 * (1.f / 512.f) - mean * mean + 1e-5f);
  unsigned short o[8] __attribute__((aligned(16)));
#pragma unroll
  for (int j = 0; j < 8; ++j) {
    float v = (a[j] - mean) * rstd * gam[n0 + j] + bet[n0 + j];
    v = v > 0.f ? v : 0.01f * v;
    o[j] = f2bf(v);
  }
  *(uint4*)(Y + row * 512 + n0) = *(const uint4*)o;
}

// ---------------------------------------------------------------------------
// ODE megakernel. A (32x512) resident in tiled LDS [mt][kk][qd][ml][8];
// 8 waves, each owning M=32 (2 mi) x N=64 (nt = 4*wv .. 4*wv+3).
// B fragments stream global->VGPR dbuf; K-loop barrier-free.
// All per-n params (bias/time/gamma/beta/bout) in 16 packed u32 regs.
// ---------------------------------------------------------------------------

// element (row, n) address in tiled A (ushort index), row < 32
static __device__ __forceinline__ int a_addr(int row, int n) {
  return (((row >> 4) * 16 + (n >> 5)) * 4 + ((n >> 3) & 3)) * 128 + (row & 15) * 8 + (n & 7);
}

static __device__ __forceinline__ void bload(const unsigned short* __restrict__ Wt, int kk,
                                             int wv, int lane, bf16x8 (&b)[4]) {
#pragma unroll
  for (int j = 0; j < 4; ++j)
    b[j] = *(const bf16x8*)(Wt + ((size_t)kk * 32 + 4 * wv + j) * 512 + (size_t)lane * 8);
}

// bb must hold Wt slabs {0,1} on entry; holds Wnext slabs {0,1} on exit.
static __device__ __forceinline__ void gemmS(const unsigned short* __restrict__ Wt,
                                             const unsigned short* __restrict__ Wnext,
                                             const unsigned short* As, int wv, int lane,
                                             bf16x8 (&bb)[2][4], floatx4 (&acc)[2][4]) {
#pragma unroll
  for (int mi = 0; mi < 2; ++mi)
#pragma unroll
    for (int j = 0; j < 4; ++j) acc[mi][j] = 0.f;
#pragma unroll 2
  for (int kk = 0; kk < 16; ++kk) {  // unroll 2 (dbuf parity), NOT full (R5-R8 lesson)
    bf16x8 a[2];
#pragma unroll
    for (int mi = 0; mi < 2; ++mi) a[mi] = *(const bf16x8*)&As[(mi * 16 + kk) * 512 + lane * 8];
#pragma unroll
    for (int mi = 0; mi < 2; ++mi)
#pragma unroll
      for (int j = 0; j < 4; ++j)
        acc[mi][j] =
            __builtin_amdgcn_mfma_f32_16x16x32_bf16(a[mi], bb[kk & 1][j], acc[mi][j], 0, 0, 0);
    // refill the just-consumed slot: kk+2 of this weight, or next weight's 0/1
    if (kk < 14) bload(Wt, kk + 2, wv, lane, bb[kk & 1]);
    else bload(Wnext, kk - 14, wv, lane, bb[kk & 1]);
  }
}

// LN + leaky epilogue; 8-wave reduction; bias/gamma/beta from REGISTERS;
// writes bf16 result into tiled As.
static __device__ __forceinline__ void ln_epi(floatx4 (&acc)[2][4], unsigned short* As,
                                              const float (&bias)[4], const float (&gm)[4],
                                              const float (&bt)[4], int wv, int lane, int tid,
                                              float2* red, float* stat) {
  const int ml = lane & 15, qd = lane >> 4;
#pragma unroll
  for (int j = 0; j < 4; ++j)
#pragma unroll
    for (int mi = 0; mi < 2; ++mi)
#pragma unroll
      for (int r = 0; r < 4; ++r) acc[mi][j][r] += bias[j];
#pragma unroll
  for (int mi = 0; mi < 2; ++mi)
#pragma unroll
    for (int r = 0; r < 4; ++r) {
      float s1 = 0.f, s2 = 0.f;
#pragma unroll
      for (int j = 0; j < 4; ++j) { float x = acc[mi][j][r]; s1 += x; s2 += x * x; }
      s1 = row16_sum(s1);
      s2 = row16_sum(s2);
      if (ml == 15) red[(mi * 16 + 4 * qd + r) * 8 + wv] = make_float2(s1, s2);
    }
  barrier_lds();  // red visible; all waves past their As a-frag reads
  if (tid < 32) {
    float S1 = 0.f, S2 = 0.f;
#pragma unroll
    for (int w = 0; w < 8; ++w) { float2 v = red[tid * 8 + w]; S1 += v.x; S2 += v.y; }
    float mean = S1 * (1.f / 512.f);
    float var = S2 * (1.f / 512.f) - mean * mean;
    stat[tid * 2] = mean;
    stat[tid * 2 + 1] = rsqrtf(var + 1e-5f);
  }
  barrier_lds();
#pragma unroll
  for (int mi = 0; mi < 2; ++mi) {
    float mr[4][2];  // per-row stats preload (j-outer ordering, R20 lesson)
#pragma unroll
    for (int r = 0; r < 4; ++r) {
      int row = mi * 16 + 4 * qd + r;
      mr[r][0] = stat[row * 2];
      mr[r][1] = stat[row * 2 + 1];
    }
#pragma unroll
    for (int j = 0; j < 4; ++j) {
      int n = (4 * wv + j) * 16 + ml;
#pragma unroll
      for (int r = 0; r < 4; ++r) {
        float x = (acc[mi][j][r] - mr[r][0]) * mr[r][1] * gm[j] + bt[j];
        x = x > 0.f ? x : 0.01f * x;
        As[a_addr(mi * 16 + 4 * qd + r, n)] = f2bf(x);
      }
    }
  }
  barrier_lds();  // As writes visible
}

// RK4 stage: k = acc + bout(reg); h fp32 regs, ksum packed bf16 pairs in LDS
// Ks (per-thread slots, no extra barriers); writes y into As; final stage
// also writes h_ode to Yb.
static __device__ __forceinline__ void stage_epi(floatx4 (&acc)[2][4], float (&h)[2][4][4],
                                                 unsigned int* Ks, unsigned short* As,
                                                 unsigned short* Yb, size_t m0,
                                                 const float (&bo4)[4], int stg, bool last,
                                                 int wv, int lane) {
  const int ml = lane & 15, qd = lane >> 4;
  barrier_lds();  // K-loop has no barriers: ensure all waves done reading As
#pragma unroll
  for (int mi = 0; mi < 2; ++mi)
#pragma unroll
    for (int j = 0; j < 4; ++j) {
      int n = (4 * wv + j) * 16 + ml;
      float bias = bo4[j];
#pragma unroll
      for (int rp = 0; rp < 2; ++rp) {
        int kidx = (mi * 8 + qd * 2 + rp) * KSP + n;
        float kv0 = acc[mi][j][2 * rp] + bias;
        float kv1 = acc[mi][j][2 * rp + 1] + bias;
        unsigned int pk = (stg != 0) ? Ks[kidx] : 0u;
        float s0 = bf2f((unsigned short)(pk & 0xffffu));
        float s1 = bf2f((unsigned short)(pk >> 16));
        float h0 = h[mi][j][2 * rp], h1 = h[mi][j][2 * rp + 1];
        float y0, y1;
        if (stg == 0)      { s0 = kv0;        s1 = kv1;        y0 = h0 + 0.125f * kv0; y1 = h1 + 0.125f * kv1; }
        else if (stg == 1) { s0 += 2.f * kv0; s1 += 2.f * kv1; y0 = h0 + 0.125f * kv0; y1 = h1 + 0.125f * kv1; }
        else if (stg == 2) { s0 += 2.f * kv0; s1 += 2.f * kv1; y0 = h0 + 0.25f * kv0;  y1 = h1 + 0.25f * kv1; }
        else {
          h0 += (1.f / 24.f) * (s0 + kv0);  // dt/6, dt=0.25
          h1 += (1.f / 24.f) * (s1 + kv1);
          h[mi][j][2 * rp] = h0; h[mi][j][2 * rp + 1] = h1;
          y0 = h0; y1 = h1;
        }
        if (stg != 3) Ks[kidx] = (unsigned int)f2bf(s0) | ((unsigned int)f2bf(s1) << 16);
        int row = mi * 16 + 4 * qd + 2 * rp;
        As[a_addr(row, n)] = f2bf(y0);
        As[a_addr(row + 1, n)] = f2bf(y1);
        if (last && stg == 3) {
          Yb[(m0 + row) * 512 + n] = f2bf(y0);
          Yb[(m0 + row + 1) * 512 + n] = f2bf(y1);
        }
      }
    }
  barrier_lds();  // As writes visible
}

__global__ __launch_bounds__(512) void ode_mega(
    unsigned short* Yb, const unsigned short* __restrict__ W1t,
    const unsigned short* __restrict__ W2t, const unsigned short* __restrict__ Wot,
    const float* __restrict__ b1, const float* __restrict__ tr, const float* __restrict__ g1,
    const float* __restrict__ be1, const float* __restrict__ b2, const float* __restrict__ g2,
    const float* __restrict__ be2, const float* __restrict__ bo) {
  __shared__ __align__(16) unsigned short As[16384];  // 32KB tiled A (32 rows)
  __shared__ float2 red[256];                         // 2KB: 32 rows x 8 waves
  __shared__ float stat[64];                          // 256B
  __shared__ __align__(16) unsigned int Ks[16 * KSP]; // 33KB RK4 ksum
  // total ~67.5KB; occupancy pinned at 1 block/CU by register grant (see hdr)

  const int tid = threadIdx.x;
  const int lane = tid & 63;
  const int wv = tid >> 6;  // 0..7
  const int ml = lane & 15;
  const int qd = lane >> 4;
  const size_t m0 = (size_t)blockIdx.x * 32;

  // start weight prefetch immediately
  bf16x8 bb[2][4];
  bload(W1t, 0, wv, lane, bb[0]);
  bload(W1t, 1, wv, lane, bb[1]);

  // per-thread params: 4 n-positions x 8 params -> 16 packed u32 regs.
  // prm[j] = { (b1|tr), (g1|be1), (b2|g2), (be2|bo) } at n=(4wv+j)*16+ml
  unsigned int prm[4][4];
#pragma unroll
  for (int j = 0; j < 4; ++j) {
    int n = (4 * wv + j) * 16 + ml;
    prm[j][0] = pk2(b1[n], tr[n]);
    prm[j][1] = pk2(g1[n], be1[n]);
    prm[j][2] = pk2(b2[n], g2[n]);
    prm[j][3] = pk2(be2[n], bo[n]);
  }

  // stage As: thread owns row r = tid>>4, chunks c = i*16 + (tid&15)
  {
    int r = tid >> 4;  // 0..31
#pragma unroll
    for (int i = 0; i < 4; ++i) {
      int c = i * 16 + (tid & 15);
      uint4 v = *(const uint4*)(Yb + (m0 + r) * 512 + c * 8);
      int dst = (((r >> 4) * 16 + (c >> 2)) * 4 + (c & 3)) * 128 + (r & 15) * 8;
      *(uint4*)(As + dst) = v;
    }
  }
  barrier_lds();

  float h[2][4][4];  // fp32 ODE state, MFMA C-layout
#pragma unroll
  for (int mi = 0; mi < 2; ++mi)
#pragma unroll
    for (int j = 0; j < 4; ++j) {
      int n = (4 * wv + j) * 16 + ml;
#pragma unroll
      for (int r = 0; r < 4; ++r) h[mi][j][r] = bf2f(As[a_addr(mi * 16 + 4 * qd + r, n)]);
    }

  for (int e = 0; e < 16; ++e) {  // 4 RK4 steps x 4 stages
    int stg = e & 3;
    float tval = 0.25f * (float)(e >> 2) + ((stg == 3) ? 0.25f : (stg ? 0.125f : 0.f));
    floatx4 acc[2][4];
    float bias[4], gm[4], bt[4];

    gemmS(W1t, W2t, As, wv, lane, bb, acc);
#pragma unroll
    for (int j = 0; j < 4; ++j) {  // layer-1 params (time row folded into bias)
      unsigned int p0 = prm[j][0], p1 = prm[j][1];
      bias[j] = lo_bf(p0) + tval * hi_bf(p0);
      gm[j] = lo_bf(p1);
      bt[j] = hi_bf(p1);
    }
    ln_epi(acc, As, bias, gm, bt, wv, lane, tid, red, stat);

    gemmS(W2t, Wot, As, wv, lane, bb, acc);
#pragma unroll
    for (int j = 0; j < 4; ++j) {  // layer-2 params
      unsigned int p2 = prm[j][2], p3 = prm[j][3];
      bias[j] = lo_bf(p2);
      gm[j] = hi_bf(p2);
      bt[j] = lo_bf(p3);
    }
    ln_epi(acc, As, bias, gm, bt, wv, lane, tid, red, stat);

    gemmS(Wot, W1t, As, wv, lane, bb, acc);  // preloads next eval's W1
    float bo4[4];
#pragma unroll
    for (int j = 0; j < 4; ++j) bo4[j] = hi_bf(prm[j][3]);
    stage_epi(acc, h, Ks, As, Yb, m0, bo4, stg, e == 15, wv, lane);
  }
}

// ---------------------------------------------------------------------------
// GRU step: gi = y_t @ W_ih, gh = h_prev @ W_hh, gates.
// grid (32, 8): 32 rows x 64 gate-cols per block, 4 waves.
// ---------------------------------------------------------------------------
__global__ __launch_bounds__(256) void gru_step(
    const unsigned short* __restrict__ Yt, const float* __restrict__ hprev,
    float* __restrict__ hnew, const unsigned short* __restrict__ Wiht,
    const unsigned short* __restrict__ Whht, const float* __restrict__ bih,
    const float* __restrict__ bhh) {
  __shared__ __align__(16) unsigned short Ay[32 * BP];
  __shared__ __align__(16) unsigned short Ah[32 * BP];
  __shared__ __align__(16) unsigned short Bg[6 * 64 * BP];
  const int tid = threadIdx.x, lane = tid & 63, wv = tid >> 6;
  const int ml = lane & 15, qd = lane >> 4;
  const int m0 = blockIdx.x * 32;
  const int j0 = blockIdx.y * 64;

  floatx4 acc[2][6];
#pragma unroll
  for (int mi = 0; mi < 2; ++mi)
#pragma unroll
    for (int g = 0; g < 6; ++g) acc[mi][g] = 0.f;

  for (int kk = 0; kk < 16; ++kk) {
    __syncthreads();
#pragma unroll
    for (int c = 0; c < 7; ++c) {
      int id = c * 256 + tid;
      if (id < 128) {
        int r = id >> 2, kc = id & 3;
        *(uint4*)(Ay + r * BP + kc * 8) =
            *(const uint4*)(Yt + (size_t)(m0 + r) * 512 + kk * 32 + kc * 8);
      } else if (id < 256) {
        int id2 = id - 128;
        int r = id2 >> 2, kc = id2 & 3;
        const float* s = hprev + (size_t)(m0 + r) * 512 + kk * 32 + kc * 8;
        unsigned short o[8] __attribute__((aligned(16)));
#pragma unroll
        for (int j = 0; j < 8; ++j) o[j] = f2bf(s[j]);
        *(uint4*)(Ah + r * BP + kc * 8) = *(const uint4*)o;
      } else {
        int id2 = id - 256;
        int g = id2 >> 8;
        int rem = id2 & 255;
        int r = rem >> 2, kc = rem & 3;
        const unsigned short* mat = (g < 3) ? Wiht : Whht;
        int gate = (g < 3) ? g : (g - 3);
        *(uint4*)(Bg + g * (64 * BP) + r * BP + kc * 8) =
            *(const uint4*)(mat + (size_t)(gate * 512 + j0 + r) * 512 + kk * 32 + kc * 8);
      }
    }
    __syncthreads();
    bf16x8 ay[2], ah[2];
#pragma unroll
    for (int mi = 0; mi < 2; ++mi) {
      ay[mi] = *(const bf16x8*)&Ay[(16 * mi + ml) * BP + qd * 8];
      ah[mi] = *(const bf16x8*)&Ah[(16 * mi + ml) * BP + qd * 8];
    }
#pragma unroll
    for (int g = 0; g < 6; ++g) {
      bf16x8 b = *(const bf16x8*)&Bg[g * (64 * BP) + (16 * wv + ml) * BP + qd * 8];
#pragma unroll
      for (int mi = 0; mi < 2; ++mi)
        acc[mi][g] = __builtin_amdgcn_mfma_f32_16x16x32_bf16((g < 3) ? ay[mi] : ah[mi], b,
                                                             acc[mi][g], 0, 0, 0);
    }
  }
  int j = j0 + 16 * wv + ml;
  float bi_r = bih[j], bi_z = bih[512 + j], bi_n = bih[1024 + j];
  float bh_r = bhh[j], bh_z = bhh[512 + j], bh_n = bhh[1024 + j];
#pragma unroll
  for (int mi = 0; mi < 2; ++mi)
#pragma unroll
    for (int r = 0; r < 4; ++r) {
      size_t row = (size_t)(m0 + 16 * mi + 4 * qd + r);
      float rg = acc[mi][0][r] + bi_r + acc[mi][3][r] + bh_r;
      rg = 1.f / (1.f + __expf(-rg));
      float zg = acc[mi][1][r] + bi_z + acc[mi][4][r] + bh_z;
      zg = 1.f / (1.f + __expf(-zg));
      float ng = tanhf(acc[mi][2][r] + bi_n + rg * (acc[mi][5][r] + bh_n));
      float hp = hprev[row * 512 + j];
      hnew[row * 512 + j] = (1.f - zg) * ng + zg * hp;
    }
}

__global__ void zero_h(float* hf) {
  int i = blockIdx.x * 256 + threadIdx.x;
  hf[i] = 0.f;
}

// ---------------------------------------------------------------------------
extern "C" void kernel_launch(void* const* d_in, const int* in_sizes, int n_in,
                              void* d_out, int out_size, void* d_ws, size_t ws_size,
                              hipStream_t stream) {
  (void)in_sizes; (void)n_in; (void)out_size; (void)ws_size;
  const float* xs    = (const float*)d_in[0];
  const float* obsW  = (const float*)d_in[1];
  const float* obsb  = (const float*)d_in[2];
  const float* obsg  = (const float*)d_in[3];
  const float* obsbe = (const float*)d_in[4];
  const float* W1    = (const float*)d_in[5];
  const float* b1    = (const float*)d_in[6];
  const float* g1    = (const float*)d_in[7];
  const float* be1   = (const float*)d_in[8];
  const float* W2    = (const float*)d_in[9];
  const float* b2    = (const float*)d_in[10];
  const float* g2    = (const float*)d_in[11];
  const float* be2   = (const float*)d_in[12];
  const float* Wo    = (const float*)d_in[13];
  const float* bo    = (const float*)d_in[14];
  const float* Wih   = (const float*)d_in[15];
  const float* bih   = (const float*)d_in[16];
  const float* Whh   = (const float*)d_in[17];
  const float* bhh   = (const float*)d_in[18];

  char* p = (char*)d_ws;
  auto take = [&](size_t bytes) { char* q = p; p += (bytes + 255) & ~(size_t)255; return q; };
  unsigned short* W1t  = (unsigned short*)take((size_t)512 * 512 * 2);
  unsigned short* W2t  = (unsigned short*)take((size_t)512 * 512 * 2);
  unsigned short* Wot  = (unsigned short*)take((size_t)512 * 512 * 2);
  unsigned short* Wiht = (unsigned short*)take((size_t)1536 * 512 * 2);
  unsigned short* Whht = (unsigned short*)take((size_t)1536 * 512 * 2);
  float* hf0 = (float*)take((size_t)1024 * 512 * 4);
  float* hf1 = (float*)take((size_t)1024 * 512 * 4);
  unsigned short* Yb = (unsigned short*)take((size_t)65536 * 512 * 2);

  dim3 tb(32, 8);
  tile_weight<<<128, 256, 0, stream>>>(W1, W1t);  // first 512 of 513 rows
  tile_weight<<<128, 256, 0, stream>>>(W2, W2t);
  tile_weight<<<128, 256, 0, stream>>>(Wo, Wot);
  transpose_f2b<<<dim3(48, 16), tb, 0, stream>>>(Wih, Wiht, 512, 1536);
  transpose_f2b<<<dim3(48, 16), tb, 0, stream>>>(Whh, Whht, 512, 1536);

  obs_embed<<<16384, 256, 0, stream>>>(xs, obsW, obsb, obsg, obsbe, Yb);

  // tr = W1 row 512 (time row), folded into layer-1 bias per eval.
  ode_mega<<<2048, 512, 0, stream>>>(Yb, W1t, W2t, Wot, b1, W1 + 512 * 512, g1, be1, b2, g2,
                                     be2, bo);

  zero_h<<<2048, 256, 0, stream>>>(hf0);
  float* hf[2] = {hf0, hf1};
  for (int t = 0; t < 64; ++t) {
    int s = t & 1, d = s ^ 1;
    float* hn = (t == 63) ? (float*)d_out : hf[d];
    gru_step<<<dim3(32, 8), 256, 0, stream>>>(Yb + (size_t)t * 1024 * 512, hf[s], hn, Wiht, Whht,
                                              bih, bhh);
  }
}

// Round 5
// 3715.184 us; speedup vs baseline: 1.4069x; 1.0425x over previous
//
#include <hip/hip_runtime.h>
#include <stdint.h>

// ---------------------------------------------------------------------------
// ODE-RNN encoder, f32 I/O, bf16 MFMA internals.
// R22: M=64 per block (8 waves, wave = M64 x N64).
// Validated cycle model (fits R19/R20/R21 counters):
//   T(M) = max(vmem 25.6K, MFMA 14.9K*M/32) + E(M),  E ~ epilogue ~ M
//   - B-weight stream = 512KB/block/GEMM through the per-CU vmem path
//     (~60 B/cyc ceiling) -> 8.5K cyc/GEMM INDEPENDENT of M. At M=32 the
//     GEMM phase is vmem-bound 1.7x over MFMA. M=16 (R20) made it dominate.
//   - M=64: rounds halve (1024 blocks), MFMA/vmem balanced (9.9K vs 8.5K).
// Registers: occupancy pinned at 2 waves/SIMD (R17-R21) -> 256 regs/wave
// budget. acc 64A + h 64V + bb 32 + prm 16 + misc ~ 210 total: fits ONLY
// because we stopped chasing 2-block residency. ks stays in LDS (32 slots).
// E-cuts: acc init = bias splat (kills bias-add pass + zero-init); stage
// consumes acc directly (bout folded into init); bload via running pointer
// (3 VALU, was ~12). FETCH_SIZE is the spill guard (must stay ~39MB).
// Carried: plain-load prefetch sink risk (R11); no global_load_lds (R12/13);
// 2-slab B dbuf; no global RK4 state (R15); GRU simple (R15/R16).
// ---------------------------------------------------------------------------

typedef __bf16 bf16x8 __attribute__((ext_vector_type(8)));
typedef float floatx4 __attribute__((ext_vector_type(4)));

#define BP 40   // gru padded B row (ushorts)
#define KSP 516 // Ks row stride (uints): 2-way bank max (free)

static __device__ __forceinline__ float bf2f(unsigned short u) {
  union { unsigned int u32; float f; } c;
  c.u32 = ((unsigned int)u) << 16;
  return c.f;
}
static __device__ __forceinline__ unsigned short f2bf(float f) {
  union { __bf16 h; unsigned short u; } c;
  c.h = (__bf16)f;  // RNE
  return c.u;
}
// packed-bf16-pair helpers (params live as u32 = lo|hi<<16)
static __device__ __forceinline__ float lo_bf(unsigned int u) {
  union { unsigned int i; float f; } c; c.i = u << 16; return c.f;
}
static __device__ __forceinline__ float hi_bf(unsigned int u) {
  union { unsigned int i; float f; } c; c.i = u & 0xffff0000u; return c.f;
}
static __device__ __forceinline__ unsigned int pk2(float a, float b) {
  return (unsigned int)f2bf(a) | ((unsigned int)f2bf(b) << 16);
}

// LDS-only barrier: does NOT drain vmcnt, so global prefetches stay in flight.
static __device__ __forceinline__ void barrier_lds() {
  __asm__ volatile("s_waitcnt lgkmcnt(0)\n\ts_barrier" ::: "memory");
}

// VALU-only 16-lane row sum via DPP row_shr chain; sum lands in lane ml==15.
static __device__ __forceinline__ float row16_sum(float v) {
  union { float f; int i; } c, d;
  c.f = v;
  d.i = __builtin_amdgcn_update_dpp(0, c.i, 0x111, 0xf, 0xf, true); c.f += d.f;
  d.i = __builtin_amdgcn_update_dpp(0, c.i, 0x112, 0xf, 0xf, true); c.f += d.f;
  d.i = __builtin_amdgcn_update_dpp(0, c.i, 0x114, 0xf, 0xf, true); c.f += d.f;
  d.i = __builtin_amdgcn_update_dpp(0, c.i, 0x118, 0xf, 0xf, true); c.f += d.f;
  return c.f;
}

// ---------------------------------------------------------------------------
// tile_weight: W (K=512 x N=512, f32 row-major) -> bf16 tiled
// [kk(16)][nt(32)][qd(4)][ml(16)][8]; element (kk,nt,qd,ml,j) = W[kk*32+qd*8+j][nt*16+ml]
// ---------------------------------------------------------------------------
__global__ void tile_weight(const float* __restrict__ src, unsigned short* __restrict__ dst) {
  int t = blockIdx.x * 256 + threadIdx.x;  // 0..32767
  int ml = t & 15, qd = (t >> 4) & 3;
  int nt = (t >> 6) & 31, kk = t >> 11;
  int n = nt * 16 + ml;
  int k0 = kk * 32 + qd * 8;
  unsigned short o[8] __attribute__((aligned(16)));
#pragma unroll
  for (int j = 0; j < 8; ++j) o[j] = f2bf(src[(size_t)(k0 + j) * 512 + n]);
  *(uint4*)(dst + (size_t)t * 8) = *(const uint4*)o;
}

// ---------------------------------------------------------------------------
// transpose + f32->bf16 (GRU weights, [n][k] flat layout)
// ---------------------------------------------------------------------------
__global__ void transpose_f2b(const float* __restrict__ src, unsigned short* __restrict__ dst,
                              int R, int C) {
  __shared__ float t[32][33];
  int c0 = blockIdx.x * 32, r0 = blockIdx.y * 32;
  int tx = threadIdx.x, ty = threadIdx.y;  // 32 x 8
#pragma unroll
  for (int i = 0; i < 32; i += 8) t[ty + i][tx] = src[(size_t)(r0 + ty + i) * C + c0 + tx];
  __syncthreads();
#pragma unroll
  for (int i = 0; i < 32; i += 8) dst[(size_t)(c0 + ty + i) * R + r0 + tx] = f2bf(t[tx][ty + i]);
}

// ---------------------------------------------------------------------------
// obs embed: y = leaky(LN(xs @ W + b)) (f32 in, bf16 out), one wave per row
// ---------------------------------------------------------------------------
__global__ __launch_bounds__(256) void obs_embed(
    const float* __restrict__ xs, const float* __restrict__ W,
    const float* __restrict__ bias, const float* __restrict__ gam,
    const float* __restrict__ bet, unsigned short* __restrict__ Y) {
  __shared__ float Wl[4096];
  const int tid = threadIdx.x, lane = tid & 63, wv = tid >> 6;
#pragma unroll
  for (int i = 0; i < 16; ++i) Wl[i * 256 + tid] = W[i * 256 + tid];
  __syncthreads();
  size_t row = (size_t)blockIdx.x * 4 + wv;
  float xf[8];
  {
    const float* xp = xs + row * 8;
#pragma unroll
    for (int k = 0; k < 8; ++k) xf[k] = xp[k];
  }
  int n0 = lane * 8;
  float a[8];
#pragma unroll
  for (int j = 0; j < 8; ++j) a[j] = bias[n0 + j];
#pragma unroll
  for (int k = 0; k < 8; ++k)
#pragma unroll
    for (int j = 0; j < 8; ++j) a[j] += xf[k] * Wl[k * 512 + n0 + j];
  float s1 = 0.f, s2 = 0.f;
#pragma unroll
  for (int j = 0; j < 8; ++j) { s1 += a[j]; s2 += a[j] * a[j]; }
#pragma unroll
  for (int off = 1; off < 64; off <<= 1) { s1 += __shfl_xor(s1, off); s2 += __shfl_xor(s2, off); }
  float mean = s1 * (1.f / 512.f);
  float rstd = rsqrtf(s2 * (1.f / 512.f) - mean * mean + 1e-5f);
  unsigned short o[8] __attribute__((aligned(16)));
#pragma unroll
  for (int j = 0; j < 8; ++j) {
    float v = (a[j] - mean) * rstd * gam[n0 + j] + bet[n0 + j];
    v = v > 0.f ? v : 0.01f * v;
    o[j] = f2bf(v);
  }
  *(uint4*)(Y + row * 512 + n0) = *(const uint4*)o;
}

// ---------------------------------------------------------------------------
// ODE megakernel, M=64. A (64x512) in tiled LDS; 8 waves, each owning ALL 64
// rows x N=64 cols (nt = 4*wv..4*wv+3). B streams global->VGPR 2-slab dbuf.
// ---------------------------------------------------------------------------

// element (row, n) address in tiled A (ushort index), row < 64
static __device__ __forceinline__ int a_addr(int row, int n) {
  return (((row >> 4) * 16 + (n >> 5)) * 4 + ((n >> 3) & 3)) * 128 + (row & 15) * 8 + (n & 7);
}

static __device__ __forceinline__ void bload(const unsigned short* __restrict__ Wt, int kk,
                                             int wvoff, bf16x8 (&b)[4]) {
  const unsigned short* p = Wt + (size_t)kk * 16384 + wvoff;
#pragma unroll
  for (int j = 0; j < 4; ++j) b[j] = *(const bf16x8*)(p + j * 512);
}

// acc initialized to bias (splat) -> bias-add pass AND zero-init both free.
// bb must hold Wt slabs {0,1} on entry; holds Wnext slabs {0,1} on exit.
static __device__ __forceinline__ void gemmS(const unsigned short* __restrict__ Wt,
                                             const unsigned short* __restrict__ Wnext,
                                             const unsigned short* As, int wvoff, int lane,
                                             const float (&bias)[4],
                                             bf16x8 (&bb)[2][4], floatx4 (&acc)[4][4]) {
#pragma unroll
  for (int mi = 0; mi < 4; ++mi)
#pragma unroll
    for (int j = 0; j < 4; ++j)
      acc[mi][j] = (floatx4){bias[j], bias[j], bias[j], bias[j]};
#pragma unroll 2
  for (int kk = 0; kk < 16; ++kk) {  // unroll 2 (dbuf parity), NOT full (R5-R8)
    bf16x8 a[4];
#pragma unroll
    for (int mi = 0; mi < 4; ++mi) a[mi] = *(const bf16x8*)&As[(mi * 16 + kk) * 512 + lane * 8];
#pragma unroll
    for (int mi = 0; mi < 4; ++mi)
#pragma unroll
      for (int j = 0; j < 4; ++j)
        acc[mi][j] =
            __builtin_amdgcn_mfma_f32_16x16x32_bf16(a[mi], bb[kk & 1][j], acc[mi][j], 0, 0, 0);
    // refill the just-consumed slot: kk+2 of this weight, or next weight's 0/1
    if (kk < 14) bload(Wt, kk + 2, wvoff, bb[kk & 1]);
    else bload(Wnext, kk - 14, wvoff, bb[kk & 1]);
  }
}

// LN + leaky epilogue; 8-wave reduction; gamma/beta from registers.
static __device__ __forceinline__ void ln_epi(floatx4 (&acc)[4][4], unsigned short* As,
                                              const float (&gm)[4], const float (&bt)[4],
                                              int wv, int lane, int tid,
                                              float2* red, float* stat) {
  const int ml = lane & 15, qd = lane >> 4;
#pragma unroll
  for (int mi = 0; mi < 4; ++mi)
#pragma unroll
    for (int r = 0; r < 4; ++r) {
      float s1 = 0.f, s2 = 0.f;
#pragma unroll
      for (int j = 0; j < 4; ++j) { float x = acc[mi][j][r]; s1 += x; s2 += x * x; }
      s1 = row16_sum(s1);
      s2 = row16_sum(s2);
      if (ml == 15) red[(mi * 16 + 4 * qd + r) * 8 + wv] = make_float2(s1, s2);
    }
  barrier_lds();  // red visible; all waves past their As a-frag reads
  if (tid < 64) {
    float S1 = 0.f, S2 = 0.f;
#pragma unroll
    for (int w = 0; w < 8; ++w) { float2 v = red[tid * 8 + w]; S1 += v.x; S2 += v.y; }
    float mean = S1 * (1.f / 512.f);
    float var = S2 * (1.f / 512.f) - mean * mean;
    stat[tid * 2] = mean;
    stat[tid * 2 + 1] = rsqrtf(var + 1e-5f);
  }
  barrier_lds();
#pragma unroll
  for (int mi = 0; mi < 4; ++mi) {
    float mean[4], rstd[4];
#pragma unroll
    for (int r = 0; r < 4; ++r) {
      int row = mi * 16 + 4 * qd + r;
      mean[r] = stat[row * 2];
      rstd[r] = stat[row * 2 + 1];
    }
#pragma unroll
    for (int j = 0; j < 4; ++j) {
      int n = (4 * wv + j) * 16 + ml;
      float sg[4];
#pragma unroll
      for (int r = 0; r < 4; ++r) sg[r] = rstd[r] * gm[j];
#pragma unroll
      for (int r = 0; r < 4; ++r) {
        float x = (acc[mi][j][r] - mean[r]) * sg[r] + bt[j];
        x = x > 0.f ? x : 0.01f * x;
        As[a_addr(mi * 16 + 4 * qd + r, n)] = f2bf(x);
      }
    }
  }
  barrier_lds();  // As writes visible
}

// RK4 stage: kv = acc (bout folded into acc init); h fp32 regs; ksum packed
// bf16 pairs in LDS Ks (per-thread slots, no extra barriers); writes y into
// As; final stage also writes h_ode to Yb.
static __device__ __forceinline__ void stage_epi(floatx4 (&acc)[4][4], float (&h)[4][4][4],
                                                 unsigned int* Ks, unsigned short* As,
                                                 unsigned short* Yb, size_t m0,
                                                 int stg, bool last, int wv, int lane) {
  const int ml = lane & 15, qd = lane >> 4;
  barrier_lds();  // K-loop has no barriers: ensure all waves done reading As
#pragma unroll
  for (int mi = 0; mi < 4; ++mi)
#pragma unroll
    for (int j = 0; j < 4; ++j) {
      int n = (4 * wv + j) * 16 + ml;
#pragma unroll
      for (int rp = 0; rp < 2; ++rp) {
        int kidx = (mi * 8 + qd * 2 + rp) * KSP + n;
        float kv0 = acc[mi][j][2 * rp];
        float kv1 = acc[mi][j][2 * rp + 1];
        unsigned int pk = (stg != 0) ? Ks[kidx] : 0u;
        float s0 = bf2f((unsigned short)(pk & 0xffffu));
        float s1 = bf2f((unsigned short)(pk >> 16));
        float h0 = h[mi][j][2 * rp], h1 = h[mi][j][2 * rp + 1];
        float y0, y1;
        if (stg == 0)      { s0 = kv0;        s1 = kv1;        y0 = h0 + 0.125f * kv0; y1 = h1 + 0.125f * kv1; }
        else if (stg == 1) { s0 += 2.f * kv0; s1 += 2.f * kv1; y0 = h0 + 0.125f * kv0; y1 = h1 + 0.125f * kv1; }
        else if (stg == 2) { s0 += 2.f * kv0; s1 += 2.f * kv1; y0 = h0 + 0.25f * kv0;  y1 = h1 + 0.25f * kv1; }
        else {
          h0 += (1.f / 24.f) * (s0 + kv0);  // dt/6, dt=0.25
          h1 += (1.f / 24.f) * (s1 + kv1);
          h[mi][j][2 * rp] = h0; h[mi][j][2 * rp + 1] = h1;
          y0 = h0; y1 = h1;
        }
        if (stg != 3) Ks[kidx] = (unsigned int)f2bf(s0) | ((unsigned int)f2bf(s1) << 16);
        int row = mi * 16 + 4 * qd + 2 * rp;
        As[a_addr(row, n)] = f2bf(y0);
        As[a_addr(row + 1, n)] = f2bf(y1);
        if (last && stg == 3) {
          Yb[(m0 + row) * 512 + n] = f2bf(y0);
          Yb[(m0 + row + 1) * 512 + n] = f2bf(y1);
        }
      }
    }
  barrier_lds();  // As writes visible
}

__global__ __launch_bounds__(512) void ode_mega(
    unsigned short* Yb, const unsigned short* __restrict__ W1t,
    const unsigned short* __restrict__ W2t, const unsigned short* __restrict__ Wot,
    const float* __restrict__ b1, const float* __restrict__ tr, const float* __restrict__ g1,
    const float* __restrict__ be1, const float* __restrict__ b2, const float* __restrict__ g2,
    const float* __restrict__ be2, const float* __restrict__ bo) {
  __shared__ __align__(16) unsigned short As[32768];  // 64KB tiled A (64 rows)
  __shared__ float2 red[512];                         // 4KB: 64 rows x 8 waves
  __shared__ float stat[128];                         // 512B
  __shared__ __align__(16) unsigned int Ks[32 * KSP]; // 66KB RK4 ksum
  // total ~134.5KB <= 160KB; 1 block/CU (pinned anyway)

  const int tid = threadIdx.x;
  const int lane = tid & 63;
  const int wv = tid >> 6;  // 0..7
  const int ml = lane & 15;
  const int qd = lane >> 4;
  const size_t m0 = (size_t)blockIdx.x * 64;
  const int wvoff = wv * 2048 + lane * 8;  // (4wv)*512 + lane*8

  // start weight prefetch immediately
  bf16x8 bb[2][4];
  bload(W1t, 0, wvoff, bb[0]);
  bload(W1t, 1, wvoff, bb[1]);

  // per-thread params: 4 n-positions x 8 params -> 16 packed u32 regs.
  // prm[j] = { (b1|tr), (g1|be1), (b2|g2), (be2|bo) } at n=(4wv+j)*16+ml
  unsigned int prm[4][4];
#pragma unroll
  for (int j = 0; j < 4; ++j) {
    int n = (4 * wv + j) * 16 + ml;
    prm[j][0] = pk2(b1[n], tr[n]);
    prm[j][1] = pk2(g1[n], be1[n]);
    prm[j][2] = pk2(b2[n], g2[n]);
    prm[j][3] = pk2(be2[n], bo[n]);
  }

  // stage As: thread owns row r = tid>>3, chunks c = (tid&7) + i*8, i=0..7
  {
    int r = tid >> 3;       // 0..63
    int c0 = tid & 7;
#pragma unroll
    for (int i = 0; i < 8; ++i) {
      int c = c0 + i * 8;   // 0..63
      uint4 v = *(const uint4*)(Yb + (m0 + r) * 512 + c * 8);
      int dst = (((r >> 4) * 16 + (c >> 2)) * 4 + (c & 3)) * 128 + (r & 15) * 8;
      *(uint4*)(As + dst) = v;
    }
  }
  barrier_lds();

  float h[4][4][4];  // fp32 ODE state, MFMA C-layout (64 elems/thread)
#pragma unroll
  for (int mi = 0; mi < 4; ++mi)
#pragma unroll
    for (int j = 0; j < 4; ++j) {
      int n = (4 * wv + j) * 16 + ml;
#pragma unroll
      for (int r = 0; r < 4; ++r) h[mi][j][r] = bf2f(As[a_addr(mi * 16 + 4 * qd + r, n)]);
    }

  for (int e = 0; e < 16; ++e) {  // 4 RK4 steps x 4 stages
    int stg = e & 3;
    float tval = 0.25f * (float)(e >> 2) + ((stg == 3) ? 0.25f : (stg ? 0.125f : 0.f));
    floatx4 acc[4][4];
    float bias[4], gm[4], bt[4];

#pragma unroll
    for (int j = 0; j < 4; ++j) {  // layer-1 params (time row folded into bias)
      unsigned int p0 = prm[j][0], p1 = prm[j][1];
      bias[j] = lo_bf(p0) + tval * hi_bf(p0);
      gm[j] = lo_bf(p1);
      bt[j] = hi_bf(p1);
    }
    gemmS(W1t, W2t, As, wvoff, lane, bias, bb, acc);
    ln_epi(acc, As, gm, bt, wv, lane, tid, red, stat);

#pragma unroll
    for (int j = 0; j < 4; ++j) {  // layer-2 params
      unsigned int p2 = prm[j][2], p3 = prm[j][3];
      bias[j] = lo_bf(p2);
      gm[j] = hi_bf(p2);
      bt[j] = lo_bf(p3);
    }
    gemmS(W2t, Wot, As, wvoff, lane, bias, bb, acc);
    ln_epi(acc, As, gm, bt, wv, lane, tid, red, stat);

    float bo4[4];
#pragma unroll
    for (int j = 0; j < 4; ++j) bo4[j] = hi_bf(prm[j][3]);
    gemmS(Wot, W1t, As, wvoff, lane, bo4, bb, acc);  // preloads next eval's W1
    stage_epi(acc, h, Ks, As, Yb, m0, stg, e == 15, wv, lane);
  }
}

// ---------------------------------------------------------------------------
// GRU step: gi = y_t @ W_ih, gh = h_prev @ W_hh, gates.
// grid (32, 8): 32 rows x 64 gate-cols per block, 4 waves.
// ---------------------------------------------------------------------------
__global__ __launch_bounds__(256) void gru_step(
    const unsigned short* __restrict__ Yt, const float* __restrict__ hprev,
    float* __restrict__ hnew, const unsigned short* __restrict__ Wiht,
    const unsigned short* __restrict__ Whht, const float* __restrict__ bih,
    const float* __restrict__ bhh) {
  __shared__ __align__(16) unsigned short Ay[32 * BP];
  __shared__ __align__(16) unsigned short Ah[32 * BP];
  __shared__ __align__(16) unsigned short Bg[6 * 64 * BP];
  const int tid = threadIdx.x, lane = tid & 63, wv = tid >> 6;
  const int ml = lane & 15, qd = lane >> 4;
  const int m0 = blockIdx.x * 32;
  const int j0 = blockIdx.y * 64;

  floatx4 acc[2][6];
#pragma unroll
  for (int mi = 0; mi < 2; ++mi)
#pragma unroll
    for (int g = 0; g < 6; ++g) acc[mi][g] = 0.f;

  for (int kk = 0; kk < 16; ++kk) {
    __syncthreads();
#pragma unroll
    for (int c = 0; c < 7; ++c) {
      int id = c * 256 + tid;
      if (id < 128) {
        int r = id >> 2, kc = id & 3;
        *(uint4*)(Ay + r * BP + kc * 8) =
            *(const uint4*)(Yt + (size_t)(m0 + r) * 512 + kk * 32 + kc * 8);
      } else if (id < 256) {
        int id2 = id - 128;
        int r = id2 >> 2, kc = id2 & 3;
        const float* s = hprev + (size_t)(m0 + r) * 512 + kk * 32 + kc * 8;
        unsigned short o[8] __attribute__((aligned(16)));
#pragma unroll
        for (int j = 0; j < 8; ++j) o[j] = f2bf(s[j]);
        *(uint4*)(Ah + r * BP + kc * 8) = *(const uint4*)o;
      } else {
        int id2 = id - 256;
        int g = id2 >> 8;
        int rem = id2 & 255;
        int r = rem >> 2, kc = rem & 3;
        const unsigned short* mat = (g < 3) ? Wiht : Whht;
        int gate = (g < 3) ? g : (g - 3);
        *(uint4*)(Bg + g * (64 * BP) + r * BP + kc * 8) =
            *(const uint4*)(mat + (size_t)(gate * 512 + j0 + r) * 512 + kk * 32 + kc * 8);
      }
    }
    __syncthreads();
    bf16x8 ay[2], ah[2];
#pragma unroll
    for (int mi = 0; mi < 2; ++mi) {
      ay[mi] = *(const bf16x8*)&Ay[(16 * mi + ml) * BP + qd * 8];
      ah[mi] = *(const bf16x8*)&Ah[(16 * mi + ml) * BP + qd * 8];
    }
#pragma unroll
    for (int g = 0; g < 6; ++g) {
      bf16x8 b = *(const bf16x8*)&Bg[g * (64 * BP) + (16 * wv + ml) * BP + qd * 8];
#pragma unroll
      for (int mi = 0; mi < 2; ++mi)
        acc[mi][g] = __builtin_amdgcn_mfma_f32_16x16x32_bf16((g < 3) ? ay[mi] : ah[mi], b,
                                                             acc[mi][g], 0, 0, 0);
    }
  }
  int j = j0 + 16 * wv + ml;
  float bi_r = bih[j], bi_z = bih[512 + j], bi_n = bih[1024 + j];
  float bh_r = bhh[j], bh_z = bhh[512 + j], bh_n = bhh[1024 + j];
#pragma unroll
  for (int mi = 0; mi < 2; ++mi)
#pragma unroll
    for (int r = 0; r < 4; ++r) {
      size_t row = (size_t)(m0 + 16 * mi + 4 * qd + r);
      float rg = acc[mi][0][r] + bi_r + acc[mi][3][r] + bh_r;
      rg = 1.f / (1.f + __expf(-rg));
      float zg = acc[mi][1][r] + bi_z + acc[mi][4][r] + bh_z;
      zg = 1.f / (1.f + __expf(-zg));
      float ng = tanhf(acc[mi][2][r] + bi_n + rg * (acc[mi][5][r] + bh_n));
      float hp = hprev[row * 512 + j];
      hnew[row * 512 + j] = (1.f - zg) * ng + zg * hp;
    }
}

__global__ void zero_h(float* hf) {
  int i = blockIdx.x * 256 + threadIdx.x;
  hf[i] = 0.f;
}

// ---------------------------------------------------------------------------
extern "C" void kernel_launch(void* const* d_in, const int* in_sizes, int n_in,
                              void* d_out, int out_size, void* d_ws, size_t ws_size,
                              hipStream_t stream) {
  (void)in_sizes; (void)n_in; (void)out_size; (void)ws_size;
  const float* xs    = (const float*)d_in[0];
  const float* obsW  = (const float*)d_in[1];
  const float* obsb  = (const float*)d_in[2];
  const float* obsg  = (const float*)d_in[3];
  const float* obsbe = (const float*)d_in[4];
  const float* W1    = (const float*)d_in[5];
  const float* b1    = (const float*)d_in[6];
  const float* g1    = (const float*)d_in[7];
  const float* be1   = (const float*)d_in[8];
  const float* W2    = (const float*)d_in[9];
  const float* b2    = (const float*)d_in[10];
  const float* g2    = (const float*)d_in[11];
  const float* be2   = (const float*)d_in[12];
  const float* Wo    = (const float*)d_in[13];
  const float* bo    = (const float*)d_in[14];
  const float* Wih   = (const float*)d_in[15];
  const float* bih   = (const float*)d_in[16];
  const float* Whh   = (const float*)d_in[17];
  const float* bhh   = (const float*)d_in[18];

  char* p = (char*)d_ws;
  auto take = [&](size_t bytes) { char* q = p; p += (bytes + 255) & ~(size_t)255; return q; };
  unsigned short* W1t  = (unsigned short*)take((size_t)512 * 512 * 2);
  unsigned short* W2t  = (unsigned short*)take((size_t)512 * 512 * 2);
  unsigned short* Wot  = (unsigned short*)take((size_t)512 * 512 * 2);
  unsigned short* Wiht = (unsigned short*)take((size_t)1536 * 512 * 2);
  unsigned short* Whht = (unsigned short*)take((size_t)1536 * 512 * 2);
  float* hf0 = (float*)take((size_t)1024 * 512 * 4);
  float* hf1 = (float*)take((size_t)1024 * 512 * 4);
  unsigned short* Yb = (unsigned short*)take((size_t)65536 * 512 * 2);

  dim3 tb(32, 8);
  tile_weight<<<128, 256, 0, stream>>>(W1, W1t);  // first 512 of 513 rows
  tile_weight<<<128, 256, 0, stream>>>(W2, W2t);
  tile_weight<<<128, 256, 0, stream>>>(Wo, Wot);
  transpose_f2b<<<dim3(48, 16), tb, 0, stream>>>(Wih, Wiht, 512, 1536);
  transpose_f2b<<<dim3(48, 16), tb, 0, stream>>>(Whh, Whht, 512, 1536);

  obs_embed<<<16384, 256, 0, stream>>>(xs, obsW, obsb, obsg, obsbe, Yb);

  // tr = W1 row 512 (time row), folded into layer-1 bias per eval.
  ode_mega<<<1024, 512, 0, stream>>>(Yb, W1t, W2t, Wot, b1, W1 + 512 * 512, g1, be1, b2, g2,
                                     be2, bo);

  zero_h<<<2048, 256, 0, stream>>>(hf0);
  float* hf[2] = {hf0, hf1};
  for (int t = 0; t < 64; ++t) {
    int s = t & 1, d = s ^ 1;
    float* hn = (t == 63) ? (float*)d_out : hf[d];
    gru_step<<<dim3(32, 8), 256, 0, stream>>>(Yb + (size_t)t * 1024 * 512, hf[s], hn, Wiht, Whht,
                                              bih, bhh);
  }
}